// Round 7
// baseline (114.767 us; speedup 1.0000x reference)
//
#include <hip/hip_runtime.h>
#include <hip/hip_bf16.h>

typedef __attribute__((ext_vector_type(8))) short bf16x8;
typedef __attribute__((ext_vector_type(4))) float f32x4;

#define T_DIM 32
#define B_DIM 8192
#define S_DIM 256
#define H_DIM 128
#define BM    64              // batch rows per chunk (proven best: R3)
#define NCH   8               // chunks per block -> 512 rows/block
#define BLOCKS_PER_T 16
// grid = 32 t * 16 = 512 blocks = 2 per CU, zero mid-kernel restarts

__device__ __forceinline__ uint32_t cvt_pk_bf16(float lo, float hi) {
  uint32_t r;
  asm("v_cvt_pk_bf16_f32 %0, %1, %2" : "=v"(r) : "v"(lo), "v"(hi));
  return r;
}

// raw barrier: order LDS (lgkmcnt) but do NOT drain in-flight global loads
#define BARRIER() asm volatile("s_waitcnt lgkmcnt(0)\n\ts_barrier" ::: "memory")

// issue chunk (c)'s 16 float4 loads (block-linear, fully coalesced)
#define ISSUE16(av, c)                                                         \
  _Pragma("unroll")                                                            \
  for (int j = 0; j < 16; ++j)                                                 \
    av[j] = A4[(size_t)(c) * 4096 + j * 256 + tid];

// convert av (f32) -> bf16 into LDS buffer (XOR-swizzled rows)
#define CONVERT16(av, LDSBUF)                                                  \
  _Pragma("unroll")                                                            \
  for (int j = 0; j < 16; ++j) {                                               \
    const int f   = j * 256 + tid;                                             \
    const int row = f >> 6;                                                    \
    const int kq  = f & 63;                                                    \
    const uint32_t lo = cvt_pk_bf16(av[j].x, av[j].y);                         \
    const uint32_t hi = cvt_pk_bf16(av[j].z, av[j].w);                         \
    const int byteoff = (row * 512 + kq * 8) ^ ((row & 7) << 4);               \
    *reinterpret_cast<uint2*>(&(LDSBUF)[byteoff]) = make_uint2(lo, hi);        \
  }

// MFMA on 64 rows x this wave's 32 cols + fused SiLU epilogue -> red[RI]
#define MFMA_EPI(LDSBUF, RI)                                                   \
  {                                                                            \
    f32x4 acc[4][2];                                                           \
    _Pragma("unroll")                                                          \
    for (int mt = 0; mt < 4; ++mt) {                                           \
      acc[mt][0] = (f32x4){0.f, 0.f, 0.f, 0.f};                                \
      acc[mt][1] = (f32x4){0.f, 0.f, 0.f, 0.f};                                \
    }                                                                          \
    _Pragma("unroll")                                                          \
    for (int mt = 0; mt < 4; ++mt) {                                           \
      const int row = mt * 16 + l15;                                           \
      bf16x8 afr[8];                                                           \
      _Pragma("unroll")                                                        \
      for (int ks = 0; ks < 8; ++ks) {                                         \
        const int byteoff =                                                    \
            (row * 512 + ks * 64 + lg * 16) ^ ((row & 7) << 4);                \
        afr[ks] = *reinterpret_cast<const bf16x8*>(&(LDSBUF)[byteoff]);        \
      }                                                                        \
      _Pragma("unroll")                                                        \
      for (int ks = 0; ks < 8; ++ks) {                                         \
        acc[mt][0] = __builtin_amdgcn_mfma_f32_16x16x32_bf16(                  \
            afr[ks], bfr[0][ks], acc[mt][0], 0, 0, 0);                         \
        acc[mt][1] = __builtin_amdgcn_mfma_f32_16x16x32_bf16(                  \
            afr[ks], bfr[1][ks], acc[mt][1], 0, 0, 0);                         \
      }                                                                        \
    }                                                                          \
    _Pragma("unroll")                                                          \
    for (int mt = 0; mt < 4; ++mt) {                                           \
      float part[4];                                                           \
      _Pragma("unroll")                                                        \
      for (int r = 0; r < 4; ++r) {                                            \
        float s = 0.f;                                                         \
        _Pragma("unroll")                                                      \
        for (int nloc = 0; nloc < 2; ++nloc) {                                 \
          const float h   = acc[mt][nloc][r] + b1c[nloc];                      \
          const float sig = 1.f / (1.f + __expf(-h));                          \
          s += h * sig * w2c[nloc];                                            \
        }                                                                      \
        s += __shfl_xor(s, 1);                                                 \
        s += __shfl_xor(s, 2);                                                 \
        s += __shfl_xor(s, 4);                                                 \
        s += __shfl_xor(s, 8);                                                 \
        part[r] = s;                                                           \
      }                                                                        \
      if (l15 == 0) {                                                          \
        _Pragma("unroll")                                                      \
        for (int r = 0; r < 4; ++r)                                            \
          red[RI][wid][mt * 16 + lg * 4 + r] = part[r];                        \
      }                                                                        \
    }                                                                          \
  }

#define OUTW(RI, cc)                                                           \
  if (tid < BM) {                                                              \
    const float o = red[RI][0][tid] + red[RI][1][tid] + red[RI][2][tid] +      \
                    red[RI][3][tid] + b2t;                                     \
    outw[(cc) * BM + tid] = o;                                                 \
  }

__global__ __launch_bounds__(256, 2) void cvar_mlp_kernel(
    const float* __restrict__ states, const float* __restrict__ W1,
    const float* __restrict__ b1, const float* __restrict__ W2,
    const float* __restrict__ b2, float* __restrict__ out)
{
  // double-buffered 64x256 bf16 states tile (row stride 512B, XOR-swizzled)
  __shared__ __align__(16) char ldsA[2][BM * 512];   // 2 x 32 KB
  __shared__ float red[2][4][BM];

  const int tid  = threadIdx.x;
  const int wid  = tid >> 6;
  const int lane = tid & 63;
  const int l15  = lane & 15;
  const int lg   = lane >> 4;          // 0..3

  // XCD-grouped: blocks with same (bidx&7) share a t-range -> W1[t] L2-local
  const int bidx = blockIdx.x;         // 0..511
  const int xcd  = bidx & 7;
  const int slot = bidx >> 3;          // 0..63
  const int t    = xcd * 4 + (slot >> 4);
  const int cg   = slot & 15;
  const int b0   = cg * (BM * NCH);    // 512 rows per block

  const float* Ag  = states + ((size_t)t * B_DIM + b0) * S_DIM;
  const f32x4* A4  = reinterpret_cast<const f32x4*>(Ag);
  const float* W1g = W1 + (size_t)t * (S_DIM * H_DIM);
  float*      outw = out + (size_t)t * B_DIM + b0;

  // ---- prologue: chunks 0 and 1 in flight immediately ----
  f32x4 avA[16], avB[16];
  ISSUE16(avA, 0);
  ISSUE16(avB, 1);

  // ---- W1 fragment preload into registers (L2; amortized over 8 chunks) ----
  // B-frag for mfma_f32_16x16x32_bf16: lane holds col n=lane&15, k=ks*32+lg*8+j
  bf16x8 bfr[2][8];
#pragma unroll
  for (int nloc = 0; nloc < 2; ++nloc) {
    const int ncol = (wid * 2 + nloc) * 16 + l15;
#pragma unroll
    for (int ks = 0; ks < 8; ++ks) {
      const int kbase = ks * 32 + lg * 8;
      float e[8];
#pragma unroll
      for (int j = 0; j < 8; ++j)
        e[j] = W1g[(size_t)(kbase + j) * H_DIM + ncol];
      union { uint32_t u[4]; bf16x8 v; } uu;
      uu.u[0] = cvt_pk_bf16(e[0], e[1]);
      uu.u[1] = cvt_pk_bf16(e[2], e[3]);
      uu.u[2] = cvt_pk_bf16(e[4], e[5]);
      uu.u[3] = cvt_pk_bf16(e[6], e[7]);
      bfr[nloc][ks] = uu.v;
    }
  }

  float b1c[2], w2c[2];
#pragma unroll
  for (int nloc = 0; nloc < 2; ++nloc) {
    const int col = (wid * 2 + nloc) * 16 + l15;
    b1c[nloc] = b1[(size_t)t * H_DIM + col];
    w2c[nloc] = W2[(size_t)t * H_DIM + col];
  }
  const float b2t = b2[t];

  // convert chunk 0, refill avA with chunk 2 -> 2 chunks always in flight
  CONVERT16(avA, ldsA[0]);
  ISSUE16(avA, 2);
  BARRIER();

  // ---- main loop, 2x unrolled; convert(c+1) waits on loads issued one full
  // segment earlier; raw barriers keep prefetch alive across iterations ----
#pragma unroll 1
  for (int c = 0; c < NCH; c += 2) {
    // segment A: compute chunk c from ldsA[0]
    MFMA_EPI(ldsA[0], 0);
    CONVERT16(avB, ldsA[1]);                    // chunk c+1 (issued >=1 seg ago)
    if (c + 3 < NCH) ISSUE16(avB, c + 3);
    BARRIER();
    OUTW(0, c);

    // segment B: compute chunk c+1 from ldsA[1]
    MFMA_EPI(ldsA[1], 1);
    if (c + 2 < NCH) {
      CONVERT16(avA, ldsA[0]);                  // chunk c+2
      if (c + 4 < NCH) ISSUE16(avA, c + 4);
    }
    BARRIER();
    OUTW(1, c + 1);
  }
}

extern "C" void kernel_launch(void* const* d_in, const int* in_sizes, int n_in,
                              void* d_out, int out_size, void* d_ws, size_t ws_size,
                              hipStream_t stream) {
  const float* states = (const float*)d_in[0];
  const float* W1     = (const float*)d_in[1];
  const float* b1     = (const float*)d_in[2];
  const float* W2     = (const float*)d_in[3];
  const float* b2     = (const float*)d_in[4];
  float* out          = (float*)d_out;

  const int grid = T_DIM * BLOCKS_PER_T;   // 512
  cvar_mlp_kernel<<<grid, 256, 0, stream>>>(states, W1, b1, W2, b2, out);
}

// Round 8
// 114.445 us; speedup vs baseline: 1.0028x; 1.0028x over previous
//
#include <hip/hip_runtime.h>
#include <hip/hip_bf16.h>

typedef __attribute__((ext_vector_type(8))) short bf16x8;
typedef __attribute__((ext_vector_type(4))) float f32x4;

#define T_DIM 32
#define B_DIM 8192
#define S_DIM 256
#define H_DIM 128
#define BM    64              // batch rows per chunk (proven best: R3)
#define NCH   8               // chunks per block -> 512 rows/block
#define BLOCKS_PER_T 16
// grid = 32 t * 16 = 512 blocks = 2 per CU, zero mid-kernel restarts

__device__ __forceinline__ uint32_t cvt_pk_bf16(float lo, float hi) {
  uint32_t r;
  asm("v_cvt_pk_bf16_f32 %0, %1, %2" : "=v"(r) : "v"(lo), "v"(hi));
  return r;
}

// raw barrier: order LDS (lgkmcnt) but do NOT drain in-flight global loads
#define BARRIER() asm volatile("s_waitcnt lgkmcnt(0)\n\ts_barrier" ::: "memory")

// issue chunk (c)'s 16 float4 loads (block-linear, fully coalesced)
#define ISSUE16(av, c)                                                         \
  _Pragma("unroll")                                                            \
  for (int j = 0; j < 16; ++j)                                                 \
    av[j] = A4[(size_t)(c) * 4096 + j * 256 + tid];

// convert av (f32) -> bf16 into LDS buffer (XOR-swizzled rows)
#define CONVERT16(av, LDSBUF)                                                  \
  _Pragma("unroll")                                                            \
  for (int j = 0; j < 16; ++j) {                                               \
    const int f   = j * 256 + tid;                                             \
    const int row = f >> 6;                                                    \
    const int kq  = f & 63;                                                    \
    const uint32_t lo = cvt_pk_bf16(av[j].x, av[j].y);                         \
    const uint32_t hi = cvt_pk_bf16(av[j].z, av[j].w);                         \
    const int byteoff = (row * 512 + kq * 8) ^ ((row & 7) << 4);               \
    *reinterpret_cast<uint2*>(&(LDSBUF)[byteoff]) = make_uint2(lo, hi);        \
  }

// MFMA on 64 rows x this wave's 32 cols + fused SiLU epilogue -> red[RI]
#define MFMA_EPI(LDSBUF, RI)                                                   \
  {                                                                            \
    f32x4 acc[4][2];                                                           \
    _Pragma("unroll")                                                          \
    for (int mt = 0; mt < 4; ++mt) {                                           \
      acc[mt][0] = (f32x4){0.f, 0.f, 0.f, 0.f};                                \
      acc[mt][1] = (f32x4){0.f, 0.f, 0.f, 0.f};                                \
    }                                                                          \
    _Pragma("unroll")                                                          \
    for (int mt = 0; mt < 4; ++mt) {                                           \
      const int row = mt * 16 + l15;                                           \
      bf16x8 afr[8];                                                           \
      _Pragma("unroll")                                                        \
      for (int ks = 0; ks < 8; ++ks) {                                         \
        const int byteoff =                                                    \
            (row * 512 + ks * 64 + lg * 16) ^ ((row & 7) << 4);                \
        afr[ks] = *reinterpret_cast<const bf16x8*>(&(LDSBUF)[byteoff]);        \
      }                                                                        \
      _Pragma("unroll")                                                        \
      for (int ks = 0; ks < 8; ++ks) {                                         \
        acc[mt][0] = __builtin_amdgcn_mfma_f32_16x16x32_bf16(                  \
            afr[ks], bfr[0][ks], acc[mt][0], 0, 0, 0);                         \
        acc[mt][1] = __builtin_amdgcn_mfma_f32_16x16x32_bf16(                  \
            afr[ks], bfr[1][ks], acc[mt][1], 0, 0, 0);                         \
      }                                                                        \
    }                                                                          \
    _Pragma("unroll")                                                          \
    for (int mt = 0; mt < 4; ++mt) {                                           \
      float part[4];                                                           \
      _Pragma("unroll")                                                        \
      for (int r = 0; r < 4; ++r) {                                            \
        float s = 0.f;                                                         \
        _Pragma("unroll")                                                      \
        for (int nloc = 0; nloc < 2; ++nloc) {                                 \
          const float h   = acc[mt][nloc][r] + b1c[nloc];                      \
          const float sig = 1.f / (1.f + __expf(-h));                          \
          s += h * sig * w2c[nloc];                                            \
        }                                                                      \
        s += __shfl_xor(s, 1);                                                 \
        s += __shfl_xor(s, 2);                                                 \
        s += __shfl_xor(s, 4);                                                 \
        s += __shfl_xor(s, 8);                                                 \
        part[r] = s;                                                           \
      }                                                                        \
      if (l15 == 0) {                                                          \
        _Pragma("unroll")                                                      \
        for (int r = 0; r < 4; ++r)                                            \
          red[RI][wid][mt * 16 + lg * 4 + r] = part[r];                        \
      }                                                                        \
    }                                                                          \
  }

#define OUTW(RI, cc)                                                           \
  if (tid < BM) {                                                              \
    const float o = red[RI][0][tid] + red[RI][1][tid] + red[RI][2][tid] +      \
                    red[RI][3][tid] + b2t;                                     \
    outw[(cc) * BM + tid] = o;                                                 \
  }

__global__ __attribute__((amdgpu_waves_per_eu(2, 2))) __launch_bounds__(256)
void cvar_mlp_kernel(
    const float* __restrict__ states, const float* __restrict__ W1,
    const float* __restrict__ b1, const float* __restrict__ W2,
    const float* __restrict__ b2, float* __restrict__ out)
{
  // double-buffered 64x256 bf16 states tile (row stride 512B, XOR-swizzled)
  __shared__ __align__(16) char ldsA[2][BM * 512];   // 2 x 32 KB
  __shared__ float red[2][4][BM];

  const int tid  = threadIdx.x;
  const int wid  = tid >> 6;
  const int lane = tid & 63;
  const int l15  = lane & 15;
  const int lg   = lane >> 4;          // 0..3

  // XCD-grouped: blocks with same (bidx&7) share a t-range -> W1[t] L2-local
  const int bidx = blockIdx.x;         // 0..511
  const int xcd  = bidx & 7;
  const int slot = bidx >> 3;          // 0..63
  const int t    = xcd * 4 + (slot >> 4);
  const int cg   = slot & 15;
  const int b0   = cg * (BM * NCH);    // 512 rows per block

  const float* Ag  = states + ((size_t)t * B_DIM + b0) * S_DIM;
  const f32x4* A4  = reinterpret_cast<const f32x4*>(Ag);
  const float* W1g = W1 + (size_t)t * (S_DIM * H_DIM);
  float*      outw = out + (size_t)t * B_DIM + b0;

  // ---- prologue: chunks 0 and 1 in flight immediately ----
  f32x4 avA[16], avB[16];
  ISSUE16(avA, 0);
  ISSUE16(avB, 1);

  // ---- W1 fragment preload into registers (L2; amortized over 8 chunks) ----
  // B-frag for mfma_f32_16x16x32_bf16: lane holds col n=lane&15, k=ks*32+lg*8+j
  bf16x8 bfr[2][8];
#pragma unroll
  for (int nloc = 0; nloc < 2; ++nloc) {
    const int ncol = (wid * 2 + nloc) * 16 + l15;
#pragma unroll
    for (int ks = 0; ks < 8; ++ks) {
      const int kbase = ks * 32 + lg * 8;
      float e[8];
#pragma unroll
      for (int j = 0; j < 8; ++j)
        e[j] = W1g[(size_t)(kbase + j) * H_DIM + ncol];
      union { uint32_t u[4]; bf16x8 v; } uu;
      uu.u[0] = cvt_pk_bf16(e[0], e[1]);
      uu.u[1] = cvt_pk_bf16(e[2], e[3]);
      uu.u[2] = cvt_pk_bf16(e[4], e[5]);
      uu.u[3] = cvt_pk_bf16(e[6], e[7]);
      bfr[nloc][ks] = uu.v;
    }
  }

  float b1c[2], w2c[2];
#pragma unroll
  for (int nloc = 0; nloc < 2; ++nloc) {
    const int col = (wid * 2 + nloc) * 16 + l15;
    b1c[nloc] = b1[(size_t)t * H_DIM + col];
    w2c[nloc] = W2[(size_t)t * H_DIM + col];
  }
  const float b2t = b2[t];

  // convert chunk 0, refill avA with chunk 2 -> 2 chunks always in flight
  CONVERT16(avA, ldsA[0]);
  ISSUE16(avA, 2);
  BARRIER();

  // ---- main loop, 2x unrolled; convert(c+1) waits on loads issued one full
  // segment earlier; raw barriers keep prefetch alive across iterations ----
#pragma unroll 1
  for (int c = 0; c < NCH; c += 2) {
    // segment A: compute chunk c from ldsA[0]
    MFMA_EPI(ldsA[0], 0);
    CONVERT16(avB, ldsA[1]);                    // chunk c+1 (issued >=1 seg ago)
    if (c + 3 < NCH) ISSUE16(avB, c + 3);
    BARRIER();
    OUTW(0, c);

    // segment B: compute chunk c+1 from ldsA[1]
    MFMA_EPI(ldsA[1], 1);
    if (c + 2 < NCH) {
      CONVERT16(avA, ldsA[0]);                  // chunk c+2
      if (c + 4 < NCH) ISSUE16(avA, c + 4);
    }
    BARRIER();
    OUTW(1, c + 1);
  }
}

extern "C" void kernel_launch(void* const* d_in, const int* in_sizes, int n_in,
                              void* d_out, int out_size, void* d_ws, size_t ws_size,
                              hipStream_t stream) {
  const float* states = (const float*)d_in[0];
  const float* W1     = (const float*)d_in[1];
  const float* b1     = (const float*)d_in[2];
  const float* W2     = (const float*)d_in[3];
  const float* b2     = (const float*)d_in[4];
  float* out          = (float*)d_out;

  const int grid = T_DIM * BLOCKS_PER_T;   // 512
  cvar_mlp_kernel<<<grid, 256, 0, stream>>>(states, W1, b1, W2, b2, out);
}

// Round 9
// 74.287 us; speedup vs baseline: 1.5449x; 1.5406x over previous
//
#include <hip/hip_runtime.h>
#include <hip/hip_bf16.h>

typedef __attribute__((ext_vector_type(8))) short bf16x8;
typedef __attribute__((ext_vector_type(4))) float f32x4;

#define T_DIM 32
#define B_DIM 8192
#define S_DIM 256
#define H_DIM 128
#define BM    16              // batch rows per chunk
#define NCH   32              // chunks per block -> 512 rows/block
#define BLOCKS_PER_T 16
// grid = 32 t * 16 = 512 blocks = 2 per CU

__device__ __forceinline__ uint32_t cvt_pk_bf16(float lo, float hi) {
  uint32_t r;
  asm("v_cvt_pk_bf16_f32 %0, %1, %2" : "=v"(r) : "v"(lo), "v"(hi));
  return r;
}

__global__ __launch_bounds__(256, 2) void cvar_mlp_kernel(
    const float* __restrict__ states, const float* __restrict__ W1,
    const float* __restrict__ b1, const float* __restrict__ W2,
    const float* __restrict__ b2, float* __restrict__ out)
{
  // quad-buffered 16x256 f32 states chunks, DMA'd linearly; source granules
  // pre-swizzled (lane ^ (row&7)) so swizzled reads are bank-balanced.
  __shared__ __align__(16) float bufs[4][BM * S_DIM];   // 4 x 16 KB
  __shared__ float red[2][4][BM];

  const int tid  = threadIdx.x;
  const int wid  = tid >> 6;           // 0..3 = H-group
  const int lane = tid & 63;
  const int l15  = lane & 15;
  const int lg   = lane >> 4;          // 0..3

  // XCD-grouped: blocks with same (bidx&7) share a t-range -> W1[t] L2-local
  const int bidx = blockIdx.x;         // 0..511
  const int xcd  = bidx & 7;
  const int slot = bidx >> 3;          // 0..63
  const int t    = xcd * 4 + (slot >> 4);
  const int cg   = slot & 15;
  const int b0   = cg * (BM * NCH);    // 512 rows per block

  const float* Ag  = states + ((size_t)t * B_DIM + b0) * S_DIM;
  const f32x4* A4  = reinterpret_cast<const f32x4*>(Ag);
  const float* W1g = W1 + (size_t)t * (S_DIM * H_DIM);
  float*      outw = out + (size_t)t * B_DIM + b0;

// DMA one chunk (16 rows x 1KB): 4 instrs/wave, one row each. LDS dest is
// wave-uniform base (HW adds lane*16); global source pre-swizzled per row.
#define DMA(c, q)                                                              \
  _Pragma("unroll")                                                            \
  for (int i = 0; i < 4; ++i) {                                                \
    const int r = wid * 4 + i;                                                 \
    __builtin_amdgcn_global_load_lds(                                          \
        (const __attribute__((address_space(1))) void*)(                       \
            A4 + (size_t)(c) * (BM * 64) + r * 64 + (lane ^ (r & 7))),         \
        (__attribute__((address_space(3))) void*)&bufs[q][r * S_DIM], 16, 0, 0); \
  }

  // ---- prologue: 3 chunks in flight immediately ----
  DMA(0, 0);
  DMA(1, 1);
  DMA(2, 2);

  // ---- W1 -> registers: this wave's 2 n-tiles (cols wid*32 .. wid*32+31) ----
  // B-frag for mfma_f32_16x16x32_bf16: lane holds col n=lane&15, k=ks*32+lg*8+j
  const int ncol0 = wid * 32 + l15;
  const int ncol1 = ncol0 + 16;
  bf16x8 bfr0[8], bfr1[8];
#pragma unroll
  for (int ks = 0; ks < 8; ++ks) {
    const int kbase = ks * 32 + lg * 8;
    float e[8];
#pragma unroll
    for (int j = 0; j < 8; ++j)
      e[j] = W1g[(size_t)(kbase + j) * H_DIM + ncol0];
    union { uint32_t u[4]; bf16x8 v; } uu;
    uu.u[0] = cvt_pk_bf16(e[0], e[1]);
    uu.u[1] = cvt_pk_bf16(e[2], e[3]);
    uu.u[2] = cvt_pk_bf16(e[4], e[5]);
    uu.u[3] = cvt_pk_bf16(e[6], e[7]);
    bfr0[ks] = uu.v;
  }
#pragma unroll
  for (int ks = 0; ks < 8; ++ks) {
    const int kbase = ks * 32 + lg * 8;
    float e[8];
#pragma unroll
    for (int j = 0; j < 8; ++j)
      e[j] = W1g[(size_t)(kbase + j) * H_DIM + ncol1];
    union { uint32_t u[4]; bf16x8 v; } uu;
    uu.u[0] = cvt_pk_bf16(e[0], e[1]);
    uu.u[1] = cvt_pk_bf16(e[2], e[3]);
    uu.u[2] = cvt_pk_bf16(e[4], e[5]);
    uu.u[3] = cvt_pk_bf16(e[6], e[7]);
    bfr1[ks] = uu.v;
  }

  const float b1c0 = b1[(size_t)t * H_DIM + ncol0];
  const float b1c1 = b1[(size_t)t * H_DIM + ncol1];
  const float w2c0 = W2[(size_t)t * H_DIM + ncol0];
  const float w2c1 = W2[(size_t)t * H_DIM + ncol1];
  const float b2t  = b2[t];

  // chunks 0..2 complete (older than W1 loads we already consumed), sync all
  asm volatile("s_waitcnt vmcnt(0) lgkmcnt(0)\n\ts_barrier" ::: "memory");

  // ---- main loop: DMA(c+3) | compute(c) | counted-vmcnt barrier | out ----
#pragma unroll 1
  for (int c = 0; c < NCH; ++c) {
    if (c + 3 < NCH) { DMA(c + 3, (c + 3) & 3); }

    const float* buf = bufs[c & 3];
    const int m7 = l15 & 7;              // row = l15
    f32x4 acc0 = {0.f, 0.f, 0.f, 0.f};
    f32x4 acc1 = {0.f, 0.f, 0.f, 0.f};
#pragma unroll
    for (int ks = 0; ks < 8; ++ks) {
      const int g = ks * 8 + lg * 2;     // 16B granule pair for k=ks*32+lg*8..+7
      const f32x4 f0 = *reinterpret_cast<const f32x4*>(
          &buf[l15 * S_DIM + ((g    ) ^ m7) * 4]);
      const f32x4 f1 = *reinterpret_cast<const f32x4*>(
          &buf[l15 * S_DIM + ((g + 1) ^ m7) * 4]);
      union { uint32_t u[4]; bf16x8 v; } uu;
      uu.u[0] = cvt_pk_bf16(f0.x, f0.y);
      uu.u[1] = cvt_pk_bf16(f0.z, f0.w);
      uu.u[2] = cvt_pk_bf16(f1.x, f1.y);
      uu.u[3] = cvt_pk_bf16(f1.z, f1.w);
      acc0 = __builtin_amdgcn_mfma_f32_16x16x32_bf16(uu.v, bfr0[ks], acc0, 0, 0, 0);
      acc1 = __builtin_amdgcn_mfma_f32_16x16x32_bf16(uu.v, bfr1[ks], acc1, 0, 0, 0);
    }

    // fused epilogue: +b1, SiLU, *W2, reduce 16 cols -> red[cb][wid]
    const int cb = c & 1;
    {
      float part[4];
#pragma unroll
      for (int r = 0; r < 4; ++r) {
        const float h0   = acc0[r] + b1c0;
        const float h1   = acc1[r] + b1c1;
        const float sig0 = 1.f / (1.f + __expf(-h0));
        const float sig1 = 1.f / (1.f + __expf(-h1));
        float s = h0 * sig0 * w2c0 + h1 * sig1 * w2c1;
        s += __shfl_xor(s, 1);
        s += __shfl_xor(s, 2);
        s += __shfl_xor(s, 4);
        s += __shfl_xor(s, 8);
        part[r] = s;
      }
      if (l15 == 0) {
#pragma unroll
        for (int r = 0; r < 4; ++r)
          red[cb][wid][lg * 4 + r] = part[r];
      }
    }

    // counted-vmcnt barrier: chunk c+1 guaranteed retired (in-order), the
    // 8 DMAs of chunks c+2/c+3 stay in flight ACROSS the barrier.
    if (c < NCH - 3) {
      asm volatile("s_waitcnt vmcnt(8) lgkmcnt(0)\n\ts_barrier" ::: "memory");
    } else if (c == NCH - 3) {
      asm volatile("s_waitcnt vmcnt(4) lgkmcnt(0)\n\ts_barrier" ::: "memory");
    } else {
      asm volatile("s_waitcnt vmcnt(0) lgkmcnt(0)\n\ts_barrier" ::: "memory");
    }

    // cross-wave H-reduce + b2, write 16 rows
    if (tid < BM) {
      const float o = red[cb][0][tid] + red[cb][1][tid] + red[cb][2][tid] +
                      red[cb][3][tid] + b2t;
      outw[c * BM + tid] = o;
    }
  }
}

extern "C" void kernel_launch(void* const* d_in, const int* in_sizes, int n_in,
                              void* d_out, int out_size, void* d_ws, size_t ws_size,
                              hipStream_t stream) {
  const float* states = (const float*)d_in[0];
  const float* W1     = (const float*)d_in[1];
  const float* b1     = (const float*)d_in[2];
  const float* W2     = (const float*)d_in[3];
  const float* b2     = (const float*)d_in[4];
  float* out          = (float*)d_out;

  const int grid = T_DIM * BLOCKS_PER_T;   // 512
  cvar_mlp_kernel<<<grid, 256, 0, stream>>>(states, W1, b1, W2, b2, out);
}

// Round 10
// 56.273 us; speedup vs baseline: 2.0395x; 1.3201x over previous
//
#include <hip/hip_runtime.h>
#include <hip/hip_bf16.h>

typedef __attribute__((ext_vector_type(8))) short bf16x8;
typedef __attribute__((ext_vector_type(4))) float f32x4;

#define T_DIM 32
#define B_DIM 8192
#define S_DIM 256
#define H_DIM 128
#define BM    64              // batch rows per chunk (proven best)
#define NCH   8               // chunks per block -> 512 rows/block
#define BLOCKS_PER_T 16
// grid = 32 t * 16 = 512 blocks = 2 per CU, zero mid-kernel restarts

__device__ __forceinline__ uint32_t cvt_pk_bf16(float lo, float hi) {
  uint32_t r;
  asm("v_cvt_pk_bf16_f32 %0, %1, %2" : "=v"(r) : "v"(lo), "v"(hi));
  return r;
}

// raw barrier: order LDS (lgkmcnt) but do NOT drain in-flight global loads
#define BARRIER() asm volatile("s_waitcnt lgkmcnt(0)\n\ts_barrier" ::: "memory")

// issue chunk (c)'s 16 float4 loads (block-linear, fully coalesced)
#define ISSUE16(av, c)                                                         \
  _Pragma("unroll")                                                            \
  for (int j = 0; j < 16; ++j)                                                 \
    av[j] = A4[(size_t)(c) * 4096 + j * 256 + tid];

// convert av (f32) -> bf16 into LDS buffer (XOR-swizzled rows)
#define CONVERT16(av, LDSBUF)                                                  \
  _Pragma("unroll")                                                            \
  for (int j = 0; j < 16; ++j) {                                               \
    const int f   = j * 256 + tid;                                             \
    const int row = f >> 6;                                                    \
    const int kq  = f & 63;                                                    \
    const uint32_t lo = cvt_pk_bf16(av[j].x, av[j].y);                         \
    const uint32_t hi = cvt_pk_bf16(av[j].z, av[j].w);                         \
    const int byteoff = (row * 512 + kq * 8) ^ ((row & 7) << 4);               \
    *reinterpret_cast<uint2*>(&(LDSBUF)[byteoff]) = make_uint2(lo, hi);        \
  }

// MFMA on 64 rows x this wave's 32 cols + fused SiLU epilogue -> red[RI]
#define MFMA_EPI(LDSBUF, RI)                                                   \
  {                                                                            \
    f32x4 acc[4][2];                                                           \
    _Pragma("unroll")                                                          \
    for (int mt = 0; mt < 4; ++mt) {                                           \
      acc[mt][0] = (f32x4){0.f, 0.f, 0.f, 0.f};                                \
      acc[mt][1] = (f32x4){0.f, 0.f, 0.f, 0.f};                                \
    }                                                                          \
    _Pragma("unroll")                                                          \
    for (int mt = 0; mt < 4; ++mt) {                                           \
      const int row = mt * 16 + l15;                                           \
      bf16x8 afr[8];                                                           \
      _Pragma("unroll")                                                        \
      for (int ks = 0; ks < 8; ++ks) {                                         \
        const int byteoff =                                                    \
            (row * 512 + ks * 64 + lg * 16) ^ ((row & 7) << 4);                \
        afr[ks] = *reinterpret_cast<const bf16x8*>(&(LDSBUF)[byteoff]);        \
      }                                                                        \
      _Pragma("unroll")                                                        \
      for (int ks = 0; ks < 8; ++ks) {                                         \
        acc[mt][0] = __builtin_amdgcn_mfma_f32_16x16x32_bf16(                  \
            afr[ks], bfr[0][ks], acc[mt][0], 0, 0, 0);                         \
        acc[mt][1] = __builtin_amdgcn_mfma_f32_16x16x32_bf16(                  \
            afr[ks], bfr[1][ks], acc[mt][1], 0, 0, 0);                         \
      }                                                                        \
    }                                                                          \
    _Pragma("unroll")                                                          \
    for (int mt = 0; mt < 4; ++mt) {                                           \
      float part[4];                                                           \
      _Pragma("unroll")                                                        \
      for (int r = 0; r < 4; ++r) {                                            \
        float s = 0.f;                                                         \
        _Pragma("unroll")                                                      \
        for (int nloc = 0; nloc < 2; ++nloc) {                                 \
          const float h   = acc[mt][nloc][r] + b1c[nloc];                      \
          const float sig = 1.f / (1.f + __expf(-h));                          \
          s += h * sig * w2c[nloc];                                            \
        }                                                                      \
        s += __shfl_xor(s, 1);                                                 \
        s += __shfl_xor(s, 2);                                                 \
        s += __shfl_xor(s, 4);                                                 \
        s += __shfl_xor(s, 8);                                                 \
        part[r] = s;                                                           \
      }                                                                        \
      if (l15 == 0) {                                                          \
        _Pragma("unroll")                                                      \
        for (int r = 0; r < 4; ++r)                                            \
          red[RI][wid][mt * 16 + lg * 4 + r] = part[r];                        \
      }                                                                        \
    }                                                                          \
  }

#define OUTW(RI, cc)                                                           \
  if (tid < BM) {                                                              \
    const float o = red[RI][0][tid] + red[RI][1][tid] + red[RI][2][tid] +      \
                    red[RI][3][tid] + b2t;                                     \
    outw[(cc) * BM + tid] = o;                                                 \
  }

__global__ __launch_bounds__(256, 2) void cvar_mlp_kernel(
    const float* __restrict__ states, const float* __restrict__ W1,
    const float* __restrict__ b1, const float* __restrict__ W2,
    const float* __restrict__ b2, float* __restrict__ out)
{
  // double-buffered 64x256 bf16 states tile (row stride 512B, XOR-swizzled)
  __shared__ __align__(16) char ldsA[2][BM * 512];   // 2 x 32 KB
  __shared__ float red[2][4][BM];

  const int tid  = threadIdx.x;
  const int wid  = tid >> 6;
  const int lane = tid & 63;
  const int l15  = lane & 15;
  const int lg   = lane >> 4;          // 0..3

  // XCD-grouped: blocks with same (bidx&7) share a t-range -> W1[t] L2-local
  const int bidx = blockIdx.x;         // 0..511
  const int xcd  = bidx & 7;
  const int slot = bidx >> 3;          // 0..63
  const int t    = xcd * 4 + (slot >> 4);
  const int cg   = slot & 15;
  const int b0   = cg * (BM * NCH);    // 512 rows per block

  const float* Ag  = states + ((size_t)t * B_DIM + b0) * S_DIM;
  const f32x4* A4  = reinterpret_cast<const f32x4*>(Ag);
  const float* W1g = W1 + (size_t)t * (S_DIM * H_DIM);
  float*      outw = out + (size_t)t * B_DIM + b0;

  // ---- prologue: chunk 0 in flight (single av buffer: stays <=128 VGPR) ----
  f32x4 av[16];
  ISSUE16(av, 0);

  // ---- W1 fragment preload into registers (L2; amortized over 8 chunks) ----
  // B-frag for mfma_f32_16x16x32_bf16: lane holds col n=lane&15, k=ks*32+lg*8+j
  bf16x8 bfr[2][8];
#pragma unroll
  for (int nloc = 0; nloc < 2; ++nloc) {
    const int ncol = (wid * 2 + nloc) * 16 + l15;
#pragma unroll
    for (int ks = 0; ks < 8; ++ks) {
      const int kbase = ks * 32 + lg * 8;
      float e[8];
#pragma unroll
      for (int j = 0; j < 8; ++j)
        e[j] = W1g[(size_t)(kbase + j) * H_DIM + ncol];
      union { uint32_t u[4]; bf16x8 v; } uu;
      uu.u[0] = cvt_pk_bf16(e[0], e[1]);
      uu.u[1] = cvt_pk_bf16(e[2], e[3]);
      uu.u[2] = cvt_pk_bf16(e[4], e[5]);
      uu.u[3] = cvt_pk_bf16(e[6], e[7]);
      bfr[nloc][ks] = uu.v;
    }
  }

  float b1c[2], w2c[2];
#pragma unroll
  for (int nloc = 0; nloc < 2; ++nloc) {
    const int col = (wid * 2 + nloc) * 16 + l15;
    b1c[nloc] = b1[(size_t)t * H_DIM + col];
    w2c[nloc] = W2[(size_t)t * H_DIM + col];
  }
  const float b2t = b2[t];

  // convert chunk 0 into lds[0]; immediately refill av with chunk 1
  CONVERT16(av, ldsA[0]);
  ISSUE16(av, 1);
  BARRIER();

  // ---- main loop, 2x unrolled. Per segment: compute(c) | convert(c+1,
  // loaded one FULL iteration ago) | issue(c+2) | lgkm-only barrier.
  // In-flight chunk always survives the barrier; av regs reused (WAR safe:
  // CONVERT consumed them before the next ISSUE re-targets them). ----
#pragma unroll 1
  for (int c = 0; c < NCH; c += 2) {
    // segment A: compute chunk c from ldsA[0]
    MFMA_EPI(ldsA[0], 0);
    CONVERT16(av, ldsA[1]);                     // chunk c+1
    if (c + 2 < NCH) ISSUE16(av, c + 2);
    BARRIER();
    OUTW(0, c);

    // segment B: compute chunk c+1 from ldsA[1]
    MFMA_EPI(ldsA[1], 1);
    if (c + 2 < NCH) {
      CONVERT16(av, ldsA[0]);                   // chunk c+2
      if (c + 3 < NCH) ISSUE16(av, c + 3);
    }
    BARRIER();
    OUTW(1, c + 1);
  }
}

extern "C" void kernel_launch(void* const* d_in, const int* in_sizes, int n_in,
                              void* d_out, int out_size, void* d_ws, size_t ws_size,
                              hipStream_t stream) {
  const float* states = (const float*)d_in[0];
  const float* W1     = (const float*)d_in[1];
  const float* b1     = (const float*)d_in[2];
  const float* W2     = (const float*)d_in[3];
  const float* b2     = (const float*)d_in[4];
  float* out          = (float*)d_out;

  const int grid = T_DIM * BLOCKS_PER_T;   // 512
  cvar_mlp_kernel<<<grid, 256, 0, stream>>>(states, W1, b1, W2, b2, out);
}